// Round 16
// baseline (434.190 us; speedup 1.0000x reference)
//
#include <hip/hip_runtime.h>
#include <hip/hip_bf16.h>
#include <math.h>
#include <stdint.h>

typedef __bf16 bf16_t;
typedef bf16_t bf16x4 __attribute__((ext_vector_type(4)));
typedef bf16_t bf16x8 __attribute__((ext_vector_type(8)));
typedef float floatx4 __attribute__((ext_vector_type(4)));

#define B_     4
#define S_     4096
#define D_     1024
#define P_     1364
#define P3_    4092      // 3*P
#define NP_    5456      // 3P + P
#define NPAD_  5504      // act row stride
#define NB_    5632      // GEMM1 N padded to 22 tiles of 256
#define KPAD_  1408      // P_ padded (K of out-GEMM, 22 K-tiles)
#define ROWS_  16384     // B*S
#define CAP_   15.0f
#define EPS_   1e-6f
#define CHUNKS_ 32
#define CLEN_   128      // S_/CHUNKS_

// ---------------- fast transcendentals (bf16-accuracy) ----------------
__device__ __forceinline__ float fast_tanh(float x) {
    x = fminf(fmaxf(x, -15.f), 15.f);
    float e = __expf(2.f * x);
    return __fdividef(e - 1.f, e + 1.f);
}
// sigmoid(CAP*tanh(g/CAP)) == sigmoid(g) to <0.002 for all g.
__device__ __forceinline__ float fast_sig(float g) {
    return __fdividef(1.f, 1.f + __expf(-g));
}

__device__ __forceinline__ void vmcnt0() {
    asm volatile("s_waitcnt vmcnt(0)" ::: "memory");
}
__device__ __forceinline__ void vmcnt6() {
    asm volatile("s_waitcnt vmcnt(6)" ::: "memory");
}
__device__ __forceinline__ void vmcnt8() {
    asm volatile("s_waitcnt vmcnt(8)" ::: "memory");
}

// ---------------- RMSNorm: x fp32 [ROWS][D] -> xn bf16 [ROWS][D] ----------------
__global__ __launch_bounds__(256) void rmsnorm_kernel(const float* __restrict__ x,
                                                      const float* __restrict__ w,
                                                      bf16_t* __restrict__ xn) {
    int row = blockIdx.x;
    int tid = threadIdx.x;
    const float4 v = ((const float4*)(x + (size_t)row * D_))[tid];
    float ss = v.x * v.x + v.y * v.y + v.z * v.z + v.w * v.w;
    #pragma unroll
    for (int off = 32; off > 0; off >>= 1) ss += __shfl_down(ss, off);
    __shared__ float red[4];
    if ((tid & 63) == 0) red[tid >> 6] = ss;
    __syncthreads();
    float tot = red[0] + red[1] + red[2] + red[3];
    float scale = rsqrtf(tot * (1.0f / (float)D_) + EPS_);
    const float4 wv = ((const float4*)w)[tid];
    bf16x4 o;
    o[0] = (bf16_t)(v.x * scale * wv.x);
    o[1] = (bf16_t)(v.y * scale * wv.y);
    o[2] = (bf16_t)(v.z * scale * wv.z);
    o[3] = (bf16_t)(v.w * scale * wv.w);
    ((bf16x4*)(xn + (size_t)row * D_))[tid] = o;
}

// ---- merged pack: W_gate+W_cell -> Wcat^T [NB_][D], and W_out -> Wout^T [D][KPAD_] ----
__global__ __launch_bounds__(256) void pack_all(const float* __restrict__ Wg,
                                                const float* __restrict__ Wc,
                                                const float* __restrict__ Wo,
                                                bf16_t* __restrict__ Wt,
                                                bf16_t* __restrict__ WtO) {
    __shared__ float tile[32][33];
    int tx = threadIdx.x & 31;
    int ty = threadIdx.x >> 5;
    int id = blockIdx.x;
    if (id < 32 * (NB_ / 32)) {          // pack_wcat part
        int kt = (id & 31) * 32;
        int nt = (id >> 5) * 32;
        #pragma unroll
        for (int i = 0; i < 4; i++) {
            int k = kt + ty + 8 * i;
            int n = nt + tx;
            float val = 0.f;
            if (n < P3_)      val = Wg[(size_t)k * P3_ + n];
            else if (n < NP_) val = Wc[(size_t)k * P_ + (n - P3_)];
            tile[ty + 8 * i][tx] = val;
        }
        __syncthreads();
        #pragma unroll
        for (int i = 0; i < 4; i++) {
            int n = nt + ty + 8 * i;
            int k = kt + tx;
            Wt[(size_t)n * D_ + k] = (bf16_t)tile[tx][ty + 8 * i];
        }
    } else {                              // pack_wout part
        int id2 = id - 32 * (NB_ / 32);
        int pt = (id2 % (KPAD_ / 32)) * 32;
        int dt = (id2 / (KPAD_ / 32)) * 32;
        #pragma unroll
        for (int i = 0; i < 4; i++) {
            int p = pt + ty + 8 * i;
            int d = dt + tx;
            float val = (p < P_) ? Wo[(size_t)p * D_ + d] : 0.f;
            tile[ty + 8 * i][tx] = val;
        }
        __syncthreads();
        #pragma unroll
        for (int i = 0; i < 4; i++) {
            int d = dt + ty + 8 * i;
            int p = pt + tx;
            WtO[(size_t)d * KPAD_ + p] = (bf16_t)tile[tx][ty + 8 * i];
        }
    }
}

// ---------------- 128x256 8-wave GEMM1: exact-grid (no dispatch tail) ----------------
// Grid = 128 m-tiles x 22 n-tiles = 2816 = EXACTLY 11 rounds of 256 CUs (the
// 256x256 tile gave 1408 = 5.5 rounds -> ~8% half-round tail; this removes it).
// Same verified protocol as r12/r13: 4 quadrant phases Q1(m01,n01) Q2(m01,n23)
// Q3(m23,n23) Q4(m23,n01); 1 barrier/phase; spread subtile-WAR staging into
// buf c (B-lo/B-hi@ph3 after B fully read @ph2; A@ph4 after A fully read @ph3);
// counted vmcnt(6) (=t+1's 6 load-units) at end-of-tile, never drains (T4).
// Zero-conflict swizzle; operand-swap mfma(B,A): acc quad = 4 consecutive cols.
// LDS/buffer: A[2kk][128r][32k]=16KB, B[2kk][256r][32k]=32KB -> 48KB; x2 = 96KB.
template <int KTOT, int LDA, int LDB, int LDC>
__global__ __launch_bounds__(512, 2) void gemm1_128(const bf16_t* __restrict__ A,
                                                    const bf16_t* __restrict__ Bt,
                                                    bf16_t* __restrict__ O) {
    constexpr int NT = KTOT / 64;
    static_assert(NT >= 4, "NT >= 4");
    __shared__ __align__(16) char smem[98304];

    const int tid  = threadIdx.x;
    const int wid  = tid >> 6;
    const int lane = tid & 63;
    const int l15  = lane & 15;
    const int sl4  = lane >> 4;
    const int sp    = sl4 ^ ((lane >> 1) & 3);          // read 16B-slot swizzle
    const int chunk = (lane & 3) ^ ((lane >> 3) & 3);   // stage-source inverse swizzle
    const int wrow = (wid >> 2) * 64;                   // 2 wave-rows of 64
    const int wcol = (wid & 3) * 64;                    // 4 wave-cols of 64

    // XCD map: each XCD owns 16 by-rows (of 128), bx-outer (B-panel L2-resident)
    const int bid = blockIdx.x;
    const int xcd = bid & 7;
    const int idx = bid >> 3;
    const int bx  = idx >> 4;            // 0..21
    const int by  = xcd * 16 + (idx & 15);
    const int m0 = by * 128, n0 = bx * 256;

    const int srow = wid * 16 + (lane >> 2);            // 0..127
    const bf16_t* Asrc = A  + (size_t)(m0 + srow) * LDA + chunk * 8;
    const bf16_t* Bsrc = Bt + (size_t)(n0 + srow) * LDB + chunk * 8;
    const unsigned ldsW = (unsigned)(wid * 1024);

    // load-units (2 global_load_lds each, one per kk): A(128r), B-lo, B-hi
    auto stageA = [&](int kt, int buf) {
        #pragma unroll
        for (int kk = 0; kk < 2; kk++)
            __builtin_amdgcn_global_load_lds(
                (const unsigned*)(Asrc + kt * 64 + kk * 32),
                (unsigned*)(smem + ((unsigned)buf * 49152u + (unsigned)kk * 8192u + ldsW)), 16, 0, 0);
    };
    auto stageBlo = [&](int kt, int buf) {
        #pragma unroll
        for (int kk = 0; kk < 2; kk++)
            __builtin_amdgcn_global_load_lds(
                (const unsigned*)(Bsrc + kt * 64 + kk * 32),
                (unsigned*)(smem + ((unsigned)buf * 49152u + 16384u + (unsigned)kk * 16384u + ldsW)), 16, 0, 0);
    };
    auto stageBhi = [&](int kt, int buf) {
        #pragma unroll
        for (int kk = 0; kk < 2; kk++)
            __builtin_amdgcn_global_load_lds(
                (const unsigned*)(Bsrc + (size_t)128 * LDB + kt * 64 + kk * 32),
                (unsigned*)(smem + ((unsigned)buf * 49152u + 16384u + (unsigned)kk * 16384u + 8192u + ldsW)), 16, 0, 0);
    };
    auto ldA = [&](int buf, int kk, int m) -> bf16x8 {   // m in 0..3, rows wrow+m*16
        return *(const bf16x8*)(smem + (buf * 49152 + kk * 8192 +
                                        (wrow + m * 16 + l15) * 64 + sp * 16));
    };
    auto ldB = [&](int buf, int kk, int n) -> bf16x8 {   // n in 0..3, rows wcol+n*16
        return *(const bf16x8*)(smem + (buf * 49152 + 16384 + kk * 16384 +
                                        (wcol + n * 16 + l15) * 64 + sp * 16));
    };

    floatx4 acc[4][4];
    #pragma unroll
    for (int m = 0; m < 4; m++)
        #pragma unroll
        for (int n = 0; n < 4; n++) acc[m][n] = (floatx4){0.f, 0.f, 0.f, 0.f};

    bf16x8 aq[4];   // A m-pair: [0..1]=kk0, [2..3]=kk1 (m0-1 then m2-3 @ph3)
    bf16x8 bq[4];   // B n0-1: [0..1]=kk0, [2..3]=kk1 (live ph1->ph4)
    bf16x8 bq2[4];  // B n2-3

    // prologue: tiles 0,1 staged (12 loads); counted wait retires tile0's 6
    stageA(0, 0); stageBlo(0, 0); stageBhi(0, 0);
    stageA(1, 1); stageBlo(1, 1); stageBhi(1, 1);
    vmcnt6();
    __builtin_amdgcn_s_barrier();

    for (int t = 0; t < NT; ++t) {
        const int c = t & 1;
        const bool st = (t + 2 < NT);

        // ---- ph1: 8 reads (A m0-1 both kk, B n0-1 both kk); MFMA Q1
        #pragma unroll
        for (int m = 0; m < 2; m++) { aq[m] = ldA(c, 0, m); aq[m + 2] = ldA(c, 1, m); }
        #pragma unroll
        for (int n = 0; n < 2; n++) { bq[n] = ldB(c, 0, n); bq[n + 2] = ldB(c, 1, n); }
        __builtin_amdgcn_s_setprio(1);
        #pragma unroll
        for (int m = 0; m < 2; m++)
            #pragma unroll
            for (int n = 0; n < 2; n++) {
                acc[m][n] = __builtin_amdgcn_mfma_f32_16x16x32_bf16(bq[n], aq[m], acc[m][n], 0, 0, 0);
                acc[m][n] = __builtin_amdgcn_mfma_f32_16x16x32_bf16(bq[n + 2], aq[m + 2], acc[m][n], 0, 0, 0);
            }
        __builtin_amdgcn_s_setprio(0);
        __builtin_amdgcn_s_barrier();

        // ---- ph2: 4 reads (B n2-3); MFMA Q2
        #pragma unroll
        for (int n = 0; n < 2; n++) { bq2[n] = ldB(c, 0, n + 2); bq2[n + 2] = ldB(c, 1, n + 2); }
        __builtin_amdgcn_s_setprio(1);
        #pragma unroll
        for (int m = 0; m < 2; m++)
            #pragma unroll
            for (int n = 0; n < 2; n++) {
                acc[m][n + 2] = __builtin_amdgcn_mfma_f32_16x16x32_bf16(bq2[n], aq[m], acc[m][n + 2], 0, 0, 0);
                acc[m][n + 2] = __builtin_amdgcn_mfma_f32_16x16x32_bf16(bq2[n + 2], aq[m + 2], acc[m][n + 2], 0, 0, 0);
            }
        __builtin_amdgcn_s_setprio(0);
        __builtin_amdgcn_s_barrier();   // all waves' B reads of buf c retired

        // ---- ph3: 4 reads (A m2-3 overwrite aq); stage B(t+2) into buf c; MFMA Q3
        #pragma unroll
        for (int m = 0; m < 2; m++) { aq[m] = ldA(c, 0, m + 2); aq[m + 2] = ldA(c, 1, m + 2); }
        if (st) { stageBlo(t + 2, c); stageBhi(t + 2, c); }
        __builtin_amdgcn_s_setprio(1);
        #pragma unroll
        for (int m = 0; m < 2; m++)
            #pragma unroll
            for (int n = 0; n < 2; n++) {
                acc[m + 2][n + 2] = __builtin_amdgcn_mfma_f32_16x16x32_bf16(bq2[n], aq[m], acc[m + 2][n + 2], 0, 0, 0);
                acc[m + 2][n + 2] = __builtin_amdgcn_mfma_f32_16x16x32_bf16(bq2[n + 2], aq[m + 2], acc[m + 2][n + 2], 0, 0, 0);
            }
        __builtin_amdgcn_s_setprio(0);
        __builtin_amdgcn_s_barrier();   // all waves' A reads of buf c retired

        // ---- ph4: stage A(t+2); reg-only Q4; counted vmcnt; publish
        if (st) stageA(t + 2, c);
        __builtin_amdgcn_s_setprio(1);
        #pragma unroll
        for (int m = 0; m < 2; m++)
            #pragma unroll
            for (int n = 0; n < 2; n++) {
                acc[m + 2][n] = __builtin_amdgcn_mfma_f32_16x16x32_bf16(bq[n], aq[m], acc[m + 2][n], 0, 0, 0);
                acc[m + 2][n] = __builtin_amdgcn_mfma_f32_16x16x32_bf16(bq[n + 2], aq[m + 2], acc[m + 2][n], 0, 0, 0);
            }
        __builtin_amdgcn_s_setprio(0);
        if (st)                vmcnt6();   // retire t+1's 6 units; t+2's stay in flight
        else if (t + 2 == NT)  vmcnt0();
        __builtin_amdgcn_s_barrier();      // publish buf c^1
    }

    // operand-swap C: rows m0+wrow+m*16+l15, 4 consecutive cols n0+wcol+n*16+sl4*4
    #pragma unroll
    for (int m = 0; m < 4; m++) {
        const int row = m0 + wrow + m * 16 + l15;
        #pragma unroll
        for (int n = 0; n < 4; n++) {
            const int cb = n0 + wcol + n * 16 + sl4 * 4;
            if (cb < NP_) {
                const bool sg = cb < P3_;
                bf16x4 o;
                #pragma unroll
                for (int r = 0; r < 4; r++) {
                    float g = acc[m][n][r];
                    o[r] = (bf16_t)(sg ? fast_sig(g) : fast_tanh(g));
                }
                *(bf16x4*)(O + (size_t)row * LDC + cb) = o;
            }
        }
    }
}

// ---------------- 256x256 8-wave GEMM2 (r13 form, residual epilogue) ----------------
template <int KTOT, int LDA, int LDB, int LDC, int NX>
__global__ __launch_bounds__(512, 2) void gemm2_256(const bf16_t* __restrict__ A,
                                                    const bf16_t* __restrict__ Bt,
                                                    const float* __restrict__ res,
                                                    float* __restrict__ O) {
    constexpr int NT = KTOT / 64;
    static_assert(NT >= 4, "NT >= 4");
    __shared__ __align__(16) char smem[131072];

    const int tid  = threadIdx.x;
    const int wid  = tid >> 6;
    const int lane = tid & 63;
    const int l15  = lane & 15;
    const int sl4  = lane >> 4;
    const int sp    = sl4 ^ ((lane >> 1) & 3);
    const int chunk = (lane & 3) ^ ((lane >> 3) & 3);
    const int wrow = (wid >> 2) * 128;
    const int wcol = (wid & 3) * 64;

    constexpr int MCH = (ROWS_ / 256) / 8;   // 8
    const int bid = blockIdx.x;
    const int xcd = bid & 7;
    const int idx = bid >> 3;
    const int bx  = idx / MCH;
    const int by  = xcd * MCH + (idx - bx * MCH);
    const int m0 = by * 256, n0 = bx * 256;

    const int srow = wid * 16 + (lane >> 2);
    const bf16_t* Asrc = A  + (size_t)(m0 + srow) * LDA + chunk * 8;
    const bf16_t* Bsrc = Bt + (size_t)(n0 + srow) * LDB + chunk * 8;
    const unsigned ldsA0 = (unsigned)(wid * 1024);
    const unsigned ldsB0 = 32768u + (unsigned)(wid * 1024);

    auto stageAlo = [&](int kt, int buf) {
        #pragma unroll
        for (int kk = 0; kk < 2; kk++)
            __builtin_amdgcn_global_load_lds(
                (const unsigned*)(Asrc + kt * 64 + kk * 32),
                (unsigned*)(smem + ((unsigned)buf * 65536u + (unsigned)kk * 16384u + ldsA0)), 16, 0, 0);
    };
    auto stageAhi = [&](int kt, int buf) {
        #pragma unroll
        for (int kk = 0; kk < 2; kk++)
            __builtin_amdgcn_global_load_lds(
                (const unsigned*)(Asrc + (size_t)128 * LDA + kt * 64 + kk * 32),
                (unsigned*)(smem + ((unsigned)buf * 65536u + (unsigned)kk * 16384u + 8192u + ldsA0)), 16, 0, 0);
    };
    auto stageBlo = [&](int kt, int buf) {
        #pragma unroll
        for (int kk = 0; kk < 2; kk++)
            __builtin_amdgcn_global_load_lds(
                (const unsigned*)(Bsrc + kt * 64 + kk * 32),
                (unsigned*)(smem + ((unsigned)buf * 65536u + (unsigned)kk * 16384u + ldsB0)), 16, 0, 0);
    };
    auto stageBhi = [&](int kt, int buf) {
        #pragma unroll
        for (int kk = 0; kk < 2; kk++)
            __builtin_amdgcn_global_load_lds(
                (const unsigned*)(Bsrc + (size_t)128 * LDB + kt * 64 + kk * 32),
                (unsigned*)(smem + ((unsigned)buf * 65536u + (unsigned)kk * 16384u + 8192u + ldsB0)), 16, 0, 0);
    };
    auto ldA = [&](int buf, int kk, int m) -> bf16x8 {
        return *(const bf16x8*)(smem + (buf * 65536 + kk * 16384 +
                                        (wrow + m * 16 + l15) * 64 + sp * 16));
    };
    auto ldB = [&](int buf, int kk, int n) -> bf16x8 {
        return *(const bf16x8*)(smem + (buf * 65536 + 32768 + kk * 16384 +
                                        (wcol + n * 16 + l15) * 64 + sp * 16));
    };

    floatx4 acc[8][4];
    #pragma unroll
    for (int m = 0; m < 8; m++)
        #pragma unroll
        for (int n = 0; n < 4; n++) acc[m][n] = (floatx4){0.f, 0.f, 0.f, 0.f};

    bf16x8 aq[8], bq[4], bq2[4];

    stageAlo(0, 0); stageAhi(0, 0); stageBlo(0, 0); stageBhi(0, 0);
    stageAlo(1, 1); stageAhi(1, 1); stageBlo(1, 1); stageBhi(1, 1);
    vmcnt8();
    __builtin_amdgcn_s_barrier();

    for (int t = 0; t < NT; ++t) {
        const int c = t & 1;
        const bool st = (t + 2 < NT);

        #pragma unroll
        for (int m = 0; m < 4; m++) { aq[m] = ldA(c, 0, m); aq[m + 4] = ldA(c, 1, m); }
        #pragma unroll
        for (int n = 0; n < 2; n++) { bq[n] = ldB(c, 0, n); bq[n + 2] = ldB(c, 1, n); }
        __builtin_amdgcn_s_setprio(1);
        #pragma unroll
        for (int m = 0; m < 4; m++)
            #pragma unroll
            for (int n = 0; n < 2; n++) {
                acc[m][n] = __builtin_amdgcn_mfma_f32_16x16x32_bf16(bq[n], aq[m], acc[m][n], 0, 0, 0);
                acc[m][n] = __builtin_amdgcn_mfma_f32_16x16x32_bf16(bq[n + 2], aq[m + 4], acc[m][n], 0, 0, 0);
            }
        __builtin_amdgcn_s_setprio(0);
        __builtin_amdgcn_s_barrier();

        #pragma unroll
        for (int n = 0; n < 2; n++) { bq2[n] = ldB(c, 0, n + 2); bq2[n + 2] = ldB(c, 1, n + 2); }
        if (st) stageBlo(t + 2, c);
        __builtin_amdgcn_s_setprio(1);
        #pragma unroll
        for (int m = 0; m < 4; m++)
            #pragma unroll
            for (int n = 0; n < 2; n++) {
                acc[m][n + 2] = __builtin_amdgcn_mfma_f32_16x16x32_bf16(bq2[n], aq[m], acc[m][n + 2], 0, 0, 0);
                acc[m][n + 2] = __builtin_amdgcn_mfma_f32_16x16x32_bf16(bq2[n + 2], aq[m + 4], acc[m][n + 2], 0, 0, 0);
            }
        __builtin_amdgcn_s_setprio(0);
        __builtin_amdgcn_s_barrier();

        #pragma unroll
        for (int m = 0; m < 4; m++) { aq[m] = ldA(c, 0, m + 4); aq[m + 4] = ldA(c, 1, m + 4); }
        if (st) stageAlo(t + 2, c);
        __builtin_amdgcn_s_setprio(1);
        #pragma unroll
        for (int m = 0; m < 4; m++)
            #pragma unroll
            for (int n = 0; n < 2; n++) {
                acc[m + 4][n + 2] = __builtin_amdgcn_mfma_f32_16x16x32_bf16(bq2[n], aq[m], acc[m + 4][n + 2], 0, 0, 0);
                acc[m + 4][n + 2] = __builtin_amdgcn_mfma_f32_16x16x32_bf16(bq2[n + 2], aq[m + 4], acc[m + 4][n + 2], 0, 0, 0);
            }
        __builtin_amdgcn_s_setprio(0);
        __builtin_amdgcn_s_barrier();

        if (st) { stageAhi(t + 2, c); stageBhi(t + 2, c); }
        __builtin_amdgcn_s_setprio(1);
        #pragma unroll
        for (int m = 0; m < 4; m++)
            #pragma unroll
            for (int n = 0; n < 2; n++) {
                acc[m + 4][n] = __builtin_amdgcn_mfma_f32_16x16x32_bf16(bq[n], aq[m], acc[m + 4][n], 0, 0, 0);
                acc[m + 4][n] = __builtin_amdgcn_mfma_f32_16x16x32_bf16(bq[n + 2], aq[m + 4], acc[m + 4][n], 0, 0, 0);
            }
        __builtin_amdgcn_s_setprio(0);
        if (st)                vmcnt8();
        else if (t + 2 == NT)  vmcnt0();
        __builtin_amdgcn_s_barrier();
    }

    #pragma unroll
    for (int m = 0; m < 8; m++) {
        const int row = m0 + wrow + m * 16 + l15;
        #pragma unroll
        for (int n = 0; n < 4; n++) {
            const int cb = n0 + wcol + n * 16 + sl4 * 4;
            const float4 rv = *(const float4*)(res + (size_t)row * LDC + cb);
            float4 ov;
            ov.x = rv.x + acc[m][n][0];
            ov.y = rv.y + acc[m][n][1];
            ov.z = rv.z + acc[m][n][2];
            ov.w = rv.w + acc[m][n][3];
            *(float4*)(O + (size_t)row * LDC + cb) = ov;
        }
    }
}

// ---------------- chunked linear recurrence (r13/r14 form) ----------------
__global__ __launch_bounds__(256) void chunk_scan1(const bf16_t* __restrict__ act,
                                                   float* __restrict__ FA) {
    int p = blockIdx.x * 256 + threadIdx.x;
    int c = blockIdx.y;
    int b = blockIdx.z;
    if (p >= P_) return;
    const bf16_t* base = act + (size_t)(b * S_ + c * CLEN_) * NPAD_;
    float F = 1.f, Acc = 0.f;
    #pragma unroll 4
    for (int t = 0; t < CLEN_; t++) {
        const bf16_t* r = base + (size_t)t * NPAD_;
        float iv = (float)r[p];
        float fv = (float)r[P_ + p];
        float tc = (float)r[P3_ + p];
        Acc = fv * Acc + iv * tc;
        F *= fv;
    }
    size_t idx = (((size_t)b * CHUNKS_ + c) * P_ + p) * 2;
    FA[idx]     = F;
    FA[idx + 1] = Acc;
}

__global__ __launch_bounds__(256) void chunk_scan0(const float* __restrict__ FA,
                                                   const float* __restrict__ h0,
                                                   float* __restrict__ H0) {
    int p = blockIdx.x * 256 + threadIdx.x;
    int b = blockIdx.y;
    if (p >= P_) return;
    float h = h0[(size_t)b * P_ + p];
    for (int c = 0; c < CHUNKS_; c++) {
        H0[((size_t)b * CHUNKS_ + c) * P_ + p] = h;
        size_t idx = (((size_t)b * CHUNKS_ + c) * P_ + p) * 2;
        h = FA[idx + 1] + FA[idx] * h;
    }
}

__global__ __launch_bounds__(256) void chunk_scan2(const bf16_t* __restrict__ act,
                                                   const float* __restrict__ H0,
                                                   bf16_t* __restrict__ outp,
                                                   float* __restrict__ hs_out) {
    int p = blockIdx.x * 256 + threadIdx.x;
    int c = blockIdx.y;
    int b = blockIdx.z;
    if (p >= KPAD_) return;
    if (p >= P_) {
        bf16_t z = (bf16_t)0.f;
        for (int t = 0; t < CLEN_; t++)
            outp[(size_t)(b * S_ + c * CLEN_ + t) * KPAD_ + p] = z;
        return;
    }
    float h = H0[((size_t)b * CHUNKS_ + c) * P_ + p];
    if (c == 0) hs_out[(size_t)b * P_ + p] = h;
    const bf16_t* base = act + (size_t)(b * S_ + c * CLEN_) * NPAD_;
    bf16_t* ob = outp + (size_t)(b * S_ + c * CLEN_) * KPAD_;
    #pragma unroll 2
    for (int t = 0; t < CLEN_; t++) {
        const bf16_t* r = base + (size_t)t * NPAD_;
        float iv = (float)r[p];
        float fv = (float)r[P_ + p];
        float ov = (float)r[2 * P_ + p];
        float tc = (float)r[P3_ + p];
        h = fv * h + iv * tc;
        ob[(size_t)t * KPAD_ + p] = (bf16_t)(ov * fast_tanh(h));
    }
}

extern "C" void kernel_launch(void* const* d_in, const int* in_sizes, int n_in,
                              void* d_out, int out_size, void* d_ws, size_t ws_size,
                              hipStream_t stream) {
    const float* x   = (const float*)d_in[0];
    const float* hs  = (const float*)d_in[1];
    const float* lnw = (const float*)d_in[2];
    const float* Wg  = (const float*)d_in[3];
    const float* Wc  = (const float*)d_in[4];
    const float* Wo  = (const float*)d_in[5];
    float* out = (float*)d_out;

    char* ws = (char*)d_ws;
    size_t off = 0;
    auto alloc = [&](size_t bytes) {
        void* p = ws + off;
        off += (bytes + 255) & ~(size_t)255;
        return p;
    };
    bf16_t* xn_outp = (bf16_t*)alloc((size_t)ROWS_ * KPAD_ * 2);   // xn then outputs
    bf16_t* act     = (bf16_t*)alloc((size_t)ROWS_ * NPAD_ * 2);
    bf16_t* WcatT   = (bf16_t*)alloc((size_t)NB_ * D_ * 2);
    bf16_t* WoutT   = (bf16_t*)alloc((size_t)D_ * KPAD_ * 2);
    float*  FA      = (float*)alloc((size_t)B_ * CHUNKS_ * P_ * 2 * 4);
    float*  H0      = (float*)alloc((size_t)B_ * CHUNKS_ * P_ * 4);

    bf16_t* xn   = xn_outp;
    bf16_t* outp = xn_outp;

    hipLaunchKernelGGL(rmsnorm_kernel, dim3(ROWS_), dim3(256), 0, stream, x, lnw, xn);
    hipLaunchKernelGGL(pack_all, dim3(32 * (NB_ / 32) + (KPAD_ / 32) * (D_ / 32)),
                       dim3(256), 0, stream, Wg, Wc, Wo, WcatT, WoutT);

    // GEMM1: 128x256 tiles -> 128 x 22 = 2816 blocks = exactly 11 rounds
    hipLaunchKernelGGL((gemm1_128<D_, D_, D_, NPAD_>),
                       dim3((ROWS_ / 128) * (NB_ / 256)), dim3(512), 0, stream,
                       xn, WcatT, act);

    hipLaunchKernelGGL(chunk_scan1, dim3(6, CHUNKS_, B_), dim3(256), 0, stream, act, FA);
    hipLaunchKernelGGL(chunk_scan0, dim3(6, B_), dim3(256), 0, stream, FA, hs, H0);
    hipLaunchKernelGGL(chunk_scan2, dim3(6, CHUNKS_, B_), dim3(256), 0, stream,
                       act, H0, outp, out + (size_t)ROWS_ * D_);

    // GEMM2: 256x256 tiles -> 4 x 64 = 256 blocks = exactly 1 round
    hipLaunchKernelGGL((gemm2_256<KPAD_, KPAD_, KPAD_, D_, D_ / 256>),
                       dim3((D_ / 256) * (ROWS_ / 256)), dim3(512), 0, stream,
                       outp, WoutT, x, (float*)d_out);
}

// Round 17
// 423.653 us; speedup vs baseline: 1.0249x; 1.0249x over previous
//
#include <hip/hip_runtime.h>
#include <hip/hip_bf16.h>
#include <math.h>
#include <stdint.h>

typedef __bf16 bf16_t;
typedef bf16_t bf16x4 __attribute__((ext_vector_type(4)));
typedef bf16_t bf16x8 __attribute__((ext_vector_type(8)));
typedef float floatx4 __attribute__((ext_vector_type(4)));

#define B_     4
#define S_     4096
#define D_     1024
#define P_     1364
#define P3_    4092      // 3*P
#define NP_    5456      // 3P + P
#define NPAD_  5504      // act row stride
#define NB_    5632      // GEMM1 N padded to 22 tiles of 256
#define KPAD_  1408      // P_ padded (K of out-GEMM, 22 K-tiles)
#define ROWS_  16384     // B*S
#define CAP_   15.0f
#define EPS_   1e-6f
#define CHUNKS_ 32
#define CLEN_   128      // S_/CHUNKS_

// ---------------- fast transcendentals (bf16-accuracy) ----------------
__device__ __forceinline__ float fast_tanh(float x) {
    x = fminf(fmaxf(x, -15.f), 15.f);
    float e = __expf(2.f * x);
    return __fdividef(e - 1.f, e + 1.f);
}
// sigmoid(CAP*tanh(g/CAP)) == sigmoid(g) to <0.002 for all g.
__device__ __forceinline__ float fast_sig(float g) {
    return __fdividef(1.f, 1.f + __expf(-g));
}

__device__ __forceinline__ void vmcnt0() {
    asm volatile("s_waitcnt vmcnt(0)" ::: "memory");
}
__device__ __forceinline__ void vmcnt8() {
    asm volatile("s_waitcnt vmcnt(8)" ::: "memory");
}

// ---------------- RMSNorm: x fp32 [ROWS][D] -> xn bf16 [ROWS][D] ----------------
__global__ __launch_bounds__(256) void rmsnorm_kernel(const float* __restrict__ x,
                                                      const float* __restrict__ w,
                                                      bf16_t* __restrict__ xn) {
    int row = blockIdx.x;
    int tid = threadIdx.x;
    const float4 v = ((const float4*)(x + (size_t)row * D_))[tid];
    float ss = v.x * v.x + v.y * v.y + v.z * v.z + v.w * v.w;
    #pragma unroll
    for (int off = 32; off > 0; off >>= 1) ss += __shfl_down(ss, off);
    __shared__ float red[4];
    if ((tid & 63) == 0) red[tid >> 6] = ss;
    __syncthreads();
    float tot = red[0] + red[1] + red[2] + red[3];
    float scale = rsqrtf(tot * (1.0f / (float)D_) + EPS_);
    const float4 wv = ((const float4*)w)[tid];
    bf16x4 o;
    o[0] = (bf16_t)(v.x * scale * wv.x);
    o[1] = (bf16_t)(v.y * scale * wv.y);
    o[2] = (bf16_t)(v.z * scale * wv.z);
    o[3] = (bf16_t)(v.w * scale * wv.w);
    ((bf16x4*)(xn + (size_t)row * D_))[tid] = o;
}

// ---- merged pack: W_gate+W_cell -> Wcat^T [NB_][D], and W_out -> Wout^T [D][KPAD_] ----
__global__ __launch_bounds__(256) void pack_all(const float* __restrict__ Wg,
                                                const float* __restrict__ Wc,
                                                const float* __restrict__ Wo,
                                                bf16_t* __restrict__ Wt,
                                                bf16_t* __restrict__ WtO) {
    __shared__ float tile[32][33];
    int tx = threadIdx.x & 31;
    int ty = threadIdx.x >> 5;
    int id = blockIdx.x;
    if (id < 32 * (NB_ / 32)) {          // pack_wcat part
        int kt = (id & 31) * 32;
        int nt = (id >> 5) * 32;
        #pragma unroll
        for (int i = 0; i < 4; i++) {
            int k = kt + ty + 8 * i;
            int n = nt + tx;
            float val = 0.f;
            if (n < P3_)      val = Wg[(size_t)k * P3_ + n];
            else if (n < NP_) val = Wc[(size_t)k * P_ + (n - P3_)];
            tile[ty + 8 * i][tx] = val;
        }
        __syncthreads();
        #pragma unroll
        for (int i = 0; i < 4; i++) {
            int n = nt + ty + 8 * i;
            int k = kt + tx;
            Wt[(size_t)n * D_ + k] = (bf16_t)tile[tx][ty + 8 * i];
        }
    } else {                              // pack_wout part
        int id2 = id - 32 * (NB_ / 32);
        int pt = (id2 % (KPAD_ / 32)) * 32;
        int dt = (id2 / (KPAD_ / 32)) * 32;
        #pragma unroll
        for (int i = 0; i < 4; i++) {
            int p = pt + ty + 8 * i;
            int d = dt + tx;
            float val = (p < P_) ? Wo[(size_t)p * D_ + d] : 0.f;
            tile[ty + 8 * i][tx] = val;
        }
        __syncthreads();
        #pragma unroll
        for (int i = 0; i < 4; i++) {
            int d = dt + ty + 8 * i;
            int p = pt + tx;
            WtO[(size_t)d * KPAD_ + p] = (bf16_t)tile[tx][ty + 8 * i];
        }
    }
}

// ---------------- 256x256 8-wave GEMM, 1 barrier/phase + spread staging (r12/r13) ----------------
// Per phase: {ds_reads; stage?; setprio; MFMA; setprio; barrier}. No pre-MFMA
// barrier (waves desync; m114 overlap). Quadrant order Q1(m0-3,n0-1)
// Q2(m0-3,n2-3) Q3(m4-7,n2-3) Q4(m4-7,n0-1); stage t+2 INTO BUF c as regions
// free: B-lo@ph2, A-lo@ph3, A-hi+B-hi@ph4. End-of-tile counted vmcnt(8)
// retires exactly t+1's 8 units (FIFO, T4); never drains mid-loop. No
// sched_barrier (m141), no per-phase lgkm drains (r9). Zero-conflict swizzle.
// Operand-swap mfma(B,A): lane acc quad = 4 consecutive output cols.
template <int KTOT, int LDA, int LDB, int LDC, int NX, int EPI>
__global__ __launch_bounds__(512, 2) void gemm8(const bf16_t* __restrict__ A,
                                                const bf16_t* __restrict__ Bt,
                                                const float* __restrict__ res,
                                                void* __restrict__ outv) {
    constexpr int NT = KTOT / 64;
    static_assert(NT >= 4, "NT >= 4");
    __shared__ __align__(16) char smem[131072];

    const int tid  = threadIdx.x;
    const int wid  = tid >> 6;
    const int lane = tid & 63;
    const int l15  = lane & 15;
    const int sl4  = lane >> 4;
    const int sp    = sl4 ^ ((lane >> 1) & 3);          // read 16B-slot swizzle
    const int chunk = (lane & 3) ^ ((lane >> 3) & 3);   // stage-source inverse swizzle
    const int wrow = (wid >> 2) * 128;
    const int wcol = (wid & 3) * 64;

    // XCD map (verified: FETCH ~= compulsory): xcd owns 8 by-rows, bx-outer
    constexpr int MCH = (ROWS_ / 256) / 8;   // 8
    const int bid = blockIdx.x;
    const int xcd = bid & 7;
    const int idx = bid >> 3;
    const int bx  = idx / MCH;
    const int by  = xcd * MCH + (idx - bx * MCH);
    const int m0 = by * 256, n0 = bx * 256;

    const int srow = wid * 16 + (lane >> 2);
    const bf16_t* Asrc = A  + (size_t)(m0 + srow) * LDA + chunk * 8;
    const bf16_t* Bsrc = Bt + (size_t)(n0 + srow) * LDB + chunk * 8;
    const unsigned ldsA0 = (unsigned)(wid * 1024);
    const unsigned ldsB0 = 32768u + (unsigned)(wid * 1024);

    // half-unit stages: 2 global_load_lds each (one per kk)
    auto stageAlo = [&](int kt, int buf) {   // A rows 0-127
        #pragma unroll
        for (int kk = 0; kk < 2; kk++)
            __builtin_amdgcn_global_load_lds(
                (const unsigned*)(Asrc + kt * 64 + kk * 32),
                (unsigned*)(smem + ((unsigned)buf * 65536u + (unsigned)kk * 16384u + ldsA0)), 16, 0, 0);
    };
    auto stageAhi = [&](int kt, int buf) {   // A rows 128-255
        #pragma unroll
        for (int kk = 0; kk < 2; kk++)
            __builtin_amdgcn_global_load_lds(
                (const unsigned*)(Asrc + (size_t)128 * LDA + kt * 64 + kk * 32),
                (unsigned*)(smem + ((unsigned)buf * 65536u + (unsigned)kk * 16384u + 8192u + ldsA0)), 16, 0, 0);
    };
    auto stageBlo = [&](int kt, int buf) {   // B rows (out-cols) 0-127
        #pragma unroll
        for (int kk = 0; kk < 2; kk++)
            __builtin_amdgcn_global_load_lds(
                (const unsigned*)(Bsrc + kt * 64 + kk * 32),
                (unsigned*)(smem + ((unsigned)buf * 65536u + (unsigned)kk * 16384u + ldsB0)), 16, 0, 0);
    };
    auto stageBhi = [&](int kt, int buf) {   // B rows 128-255
        #pragma unroll
        for (int kk = 0; kk < 2; kk++)
            __builtin_amdgcn_global_load_lds(
                (const unsigned*)(Bsrc + (size_t)128 * LDB + kt * 64 + kk * 32),
                (unsigned*)(smem + ((unsigned)buf * 65536u + (unsigned)kk * 16384u + 8192u + ldsB0)), 16, 0, 0);
    };
    auto ldA = [&](int buf, int kk, int m) -> bf16x8 {
        return *(const bf16x8*)(smem + (buf * 65536 + kk * 16384 +
                                        (wrow + m * 16 + l15) * 64 + sp * 16));
    };
    auto ldB = [&](int buf, int kk, int n) -> bf16x8 {
        return *(const bf16x8*)(smem + (buf * 65536 + 32768 + kk * 16384 +
                                        (wcol + n * 16 + l15) * 64 + sp * 16));
    };

    floatx4 acc[8][4];
    #pragma unroll
    for (int m = 0; m < 8; m++)
        #pragma unroll
        for (int n = 0; n < 4; n++) acc[m][n] = (floatx4){0.f, 0.f, 0.f, 0.f};

    bf16x8 aq[8];   // A: [0..3]=kk0 m-set, [4..7]=kk1 m-set (lo then hi, rotated ph3)
    bf16x8 bq[4];   // B n0-1: live ph1 -> ph4
    bf16x8 bq2[4];  // B n2-3

    // prologue: tiles 0,1 fully staged (16 loads); counted wait retires tile0
    stageAlo(0, 0); stageAhi(0, 0); stageBlo(0, 0); stageBhi(0, 0);
    stageAlo(1, 1); stageAhi(1, 1); stageBlo(1, 1); stageBhi(1, 1);
    vmcnt8();
    __builtin_amdgcn_s_barrier();

    for (int t = 0; t < NT; ++t) {
        const int c = t & 1;
        const bool st = (t + 2 < NT);

        // ---- ph1: 12 reads (A-lo both kk, B-lo both kk); MFMA Q1
        #pragma unroll
        for (int m = 0; m < 4; m++) { aq[m] = ldA(c, 0, m); aq[m + 4] = ldA(c, 1, m); }
        #pragma unroll
        for (int n = 0; n < 2; n++) { bq[n] = ldB(c, 0, n); bq[n + 2] = ldB(c, 1, n); }
        __builtin_amdgcn_s_setprio(1);
        #pragma unroll
        for (int m = 0; m < 4; m++)
            #pragma unroll
            for (int n = 0; n < 2; n++) {
                acc[m][n] = __builtin_amdgcn_mfma_f32_16x16x32_bf16(bq[n], aq[m], acc[m][n], 0, 0, 0);
                acc[m][n] = __builtin_amdgcn_mfma_f32_16x16x32_bf16(bq[n + 2], aq[m + 4], acc[m][n], 0, 0, 0);
            }
        __builtin_amdgcn_s_setprio(0);
        __builtin_amdgcn_s_barrier();   // all waves' A-lo/B-lo reads retired

        // ---- ph2: 4 reads (B-hi); stage B-lo(t+2) into freed region; MFMA Q2
        #pragma unroll
        for (int n = 0; n < 2; n++) { bq2[n] = ldB(c, 0, n + 2); bq2[n + 2] = ldB(c, 1, n + 2); }
        if (st) stageBlo(t + 2, c);
        __builtin_amdgcn_s_setprio(1);
        #pragma unroll
        for (int m = 0; m < 4; m++)
            #pragma unroll
            for (int n = 0; n < 2; n++) {
                acc[m][n + 2] = __builtin_amdgcn_mfma_f32_16x16x32_bf16(bq2[n], aq[m], acc[m][n + 2], 0, 0, 0);
                acc[m][n + 2] = __builtin_amdgcn_mfma_f32_16x16x32_bf16(bq2[n + 2], aq[m + 4], acc[m][n + 2], 0, 0, 0);
            }
        __builtin_amdgcn_s_setprio(0);
        __builtin_amdgcn_s_barrier();

        // ---- ph3: 8 reads (A-hi overwrite aq); stage A-lo(t+2); MFMA Q3
        #pragma unroll
        for (int m = 0; m < 4; m++) { aq[m] = ldA(c, 0, m + 4); aq[m + 4] = ldA(c, 1, m + 4); }
        if (st) stageAlo(t + 2, c);
        __builtin_amdgcn_s_setprio(1);
        #pragma unroll
        for (int m = 0; m < 4; m++)
            #pragma unroll
            for (int n = 0; n < 2; n++) {
                acc[m + 4][n + 2] = __builtin_amdgcn_mfma_f32_16x16x32_bf16(bq2[n], aq[m], acc[m + 4][n + 2], 0, 0, 0);
                acc[m + 4][n + 2] = __builtin_amdgcn_mfma_f32_16x16x32_bf16(bq2[n + 2], aq[m + 4], acc[m + 4][n + 2], 0, 0, 0);
            }
        __builtin_amdgcn_s_setprio(0);
        __builtin_amdgcn_s_barrier();   // all waves' A-hi/B-hi reads retired

        // ---- ph4: stage A-hi+B-hi(t+2); reg-only Q4; counted vmcnt; publish
        if (st) { stageAhi(t + 2, c); stageBhi(t + 2, c); }
        __builtin_amdgcn_s_setprio(1);
        #pragma unroll
        for (int m = 0; m < 4; m++)
            #pragma unroll
            for (int n = 0; n < 2; n++) {
                acc[m + 4][n] = __builtin_amdgcn_mfma_f32_16x16x32_bf16(bq[n], aq[m], acc[m + 4][n], 0, 0, 0);
                acc[m + 4][n] = __builtin_amdgcn_mfma_f32_16x16x32_bf16(bq[n + 2], aq[m + 4], acc[m + 4][n], 0, 0, 0);
            }
        __builtin_amdgcn_s_setprio(0);
        if (st)                vmcnt8();   // retire t+1's 8 units; t+2's stay in flight
        else if (t + 2 == NT)  vmcnt0();   // tail: only t+1's units outstanding
        __builtin_amdgcn_s_barrier();      // publish buf c^1
    }

    // transposed C/D (operand swap): lane holds rows m0+wrow+m*16+l15,
    // 4 consecutive cols n0+wcol+n*16+sl4*4 .. +3
    if constexpr (EPI == 0) {
        bf16_t* O = (bf16_t*)outv;
        #pragma unroll
        for (int m = 0; m < 8; m++) {
            const int row = m0 + wrow + m * 16 + l15;
            #pragma unroll
            for (int n = 0; n < 4; n++) {
                const int cb = n0 + wcol + n * 16 + sl4 * 4;
                if (cb < NP_) {           // packs never straddle NP_/P3_ (all %4==0)
                    const bool sg = cb < P3_;
                    bf16x4 o;
                    #pragma unroll
                    for (int r = 0; r < 4; r++) {
                        float g = acc[m][n][r];
                        o[r] = (bf16_t)(sg ? fast_sig(g) : fast_tanh(g));
                    }
                    *(bf16x4*)(O + (size_t)row * LDC + cb) = o;
                }
            }
        }
    } else {
        float* O = (float*)outv;
        #pragma unroll
        for (int m = 0; m < 8; m++) {
            const int row = m0 + wrow + m * 16 + l15;
            #pragma unroll
            for (int n = 0; n < 4; n++) {
                const int cb = n0 + wcol + n * 16 + sl4 * 4;
                const float4 rv = *(const float4*)(res + (size_t)row * LDC + cb);
                float4 ov;
                ov.x = rv.x + acc[m][n][0];
                ov.y = rv.y + acc[m][n][1];
                ov.z = rv.z + acc[m][n][2];
                ov.w = rv.w + acc[m][n][3];
                *(float4*)(O + (size_t)row * LDC + cb) = ov;
            }
        }
    }
}

// ---------------- chunked linear recurrence (r13/r14 form) ----------------
__global__ __launch_bounds__(256) void chunk_scan1(const bf16_t* __restrict__ act,
                                                   float* __restrict__ FA) {
    int p = blockIdx.x * 256 + threadIdx.x;
    int c = blockIdx.y;
    int b = blockIdx.z;
    if (p >= P_) return;
    const bf16_t* base = act + (size_t)(b * S_ + c * CLEN_) * NPAD_;
    float F = 1.f, Acc = 0.f;
    #pragma unroll 4
    for (int t = 0; t < CLEN_; t++) {
        const bf16_t* r = base + (size_t)t * NPAD_;
        float iv = (float)r[p];
        float fv = (float)r[P_ + p];
        float tc = (float)r[P3_ + p];
        Acc = fv * Acc + iv * tc;
        F *= fv;
    }
    size_t idx = (((size_t)b * CHUNKS_ + c) * P_ + p) * 2;
    FA[idx]     = F;
    FA[idx + 1] = Acc;
}

__global__ __launch_bounds__(256) void chunk_scan0(const float* __restrict__ FA,
                                                   const float* __restrict__ h0,
                                                   float* __restrict__ H0) {
    int p = blockIdx.x * 256 + threadIdx.x;
    int b = blockIdx.y;
    if (p >= P_) return;
    float h = h0[(size_t)b * P_ + p];
    for (int c = 0; c < CHUNKS_; c++) {
        H0[((size_t)b * CHUNKS_ + c) * P_ + p] = h;
        size_t idx = (((size_t)b * CHUNKS_ + c) * P_ + p) * 2;
        h = FA[idx + 1] + FA[idx] * h;
    }
}

__global__ __launch_bounds__(256) void chunk_scan2(const bf16_t* __restrict__ act,
                                                   const float* __restrict__ H0,
                                                   bf16_t* __restrict__ outp,
                                                   float* __restrict__ hs_out) {
    int p = blockIdx.x * 256 + threadIdx.x;
    int c = blockIdx.y;
    int b = blockIdx.z;
    if (p >= KPAD_) return;
    if (p >= P_) {
        bf16_t z = (bf16_t)0.f;
        for (int t = 0; t < CLEN_; t++)
            outp[(size_t)(b * S_ + c * CLEN_ + t) * KPAD_ + p] = z;
        return;
    }
    float h = H0[((size_t)b * CHUNKS_ + c) * P_ + p];
    if (c == 0) hs_out[(size_t)b * P_ + p] = h;   // fused copy_hidden (H0[0] == hs)
    const bf16_t* base = act + (size_t)(b * S_ + c * CLEN_) * NPAD_;
    bf16_t* ob = outp + (size_t)(b * S_ + c * CLEN_) * KPAD_;
    #pragma unroll 2
    for (int t = 0; t < CLEN_; t++) {
        const bf16_t* r = base + (size_t)t * NPAD_;
        float iv = (float)r[p];
        float fv = (float)r[P_ + p];
        float ov = (float)r[2 * P_ + p];
        float tc = (float)r[P3_ + p];
        h = fv * h + iv * tc;
        ob[(size_t)t * KPAD_ + p] = (bf16_t)(ov * fast_tanh(h));
    }
}

extern "C" void kernel_launch(void* const* d_in, const int* in_sizes, int n_in,
                              void* d_out, int out_size, void* d_ws, size_t ws_size,
                              hipStream_t stream) {
    const float* x   = (const float*)d_in[0];
    const float* hs  = (const float*)d_in[1];
    const float* lnw = (const float*)d_in[2];
    const float* Wg  = (const float*)d_in[3];
    const float* Wc  = (const float*)d_in[4];
    const float* Wo  = (const float*)d_in[5];
    float* out = (float*)d_out;

    char* ws = (char*)d_ws;
    size_t off = 0;
    auto alloc = [&](size_t bytes) {
        void* p = ws + off;
        off += (bytes + 255) & ~(size_t)255;
        return p;
    };
    bf16_t* xn_outp = (bf16_t*)alloc((size_t)ROWS_ * KPAD_ * 2);   // xn then outputs
    bf16_t* act     = (bf16_t*)alloc((size_t)ROWS_ * NPAD_ * 2);
    bf16_t* WcatT   = (bf16_t*)alloc((size_t)NB_ * D_ * 2);
    bf16_t* WoutT   = (bf16_t*)alloc((size_t)D_ * KPAD_ * 2);
    float*  FA      = (float*)alloc((size_t)B_ * CHUNKS_ * P_ * 2 * 4);
    float*  H0      = (float*)alloc((size_t)B_ * CHUNKS_ * P_ * 4);

    bf16_t* xn   = xn_outp;
    bf16_t* outp = xn_outp;

    hipLaunchKernelGGL(rmsnorm_kernel, dim3(ROWS_), dim3(256), 0, stream, x, lnw, xn);
    hipLaunchKernelGGL(pack_all, dim3(32 * (NB_ / 32) + (KPAD_ / 32) * (D_ / 32)),
                       dim3(256), 0, stream, Wg, Wc, Wo, WcatT, WoutT);

    hipLaunchKernelGGL((gemm8<D_, D_, D_, NPAD_, NB_ / 256, 0>),
                       dim3((NB_ / 256) * (ROWS_ / 256)), dim3(512), 0, stream,
                       xn, WcatT, (const float*)nullptr, (void*)act);

    hipLaunchKernelGGL(chunk_scan1, dim3(6, CHUNKS_, B_), dim3(256), 0, stream, act, FA);
    hipLaunchKernelGGL(chunk_scan0, dim3(6, B_), dim3(256), 0, stream, FA, hs, H0);
    hipLaunchKernelGGL(chunk_scan2, dim3(6, CHUNKS_, B_), dim3(256), 0, stream,
                       act, H0, outp, out + (size_t)ROWS_ * D_);

    hipLaunchKernelGGL((gemm8<KPAD_, KPAD_, KPAD_, D_, D_ / 256, 1>),
                       dim3((D_ / 256) * (ROWS_ / 256)), dim3(512), 0, stream,
                       outp, WoutT, x, d_out);
}

// Round 19
// 422.232 us; speedup vs baseline: 1.0283x; 1.0034x over previous
//
#include <hip/hip_runtime.h>
#include <hip/hip_bf16.h>
#include <math.h>
#include <stdint.h>

typedef __bf16 bf16_t;
typedef bf16_t bf16x4 __attribute__((ext_vector_type(4)));
typedef bf16_t bf16x8 __attribute__((ext_vector_type(8)));
typedef float floatx4 __attribute__((ext_vector_type(4)));

#define B_     4
#define S_     4096
#define D_     1024
#define P_     1364
#define P3_    4092      // 3*P
#define NP_    5456      // 3P + P
#define NPAD_  5504      // act row stride
#define NB_    5632      // GEMM1 N padded to 22 tiles of 256
#define KPAD_  1408      // P_ padded (K of out-GEMM, 22 K-tiles)
#define ROWS_  16384     // B*S
#define CAP_   15.0f
#define EPS_   1e-6f
#define CHUNKS_ 32
#define CLEN_   128      // S_/CHUNKS_

// ---------------- fast transcendentals (bf16-accuracy) ----------------
__device__ __forceinline__ float fast_tanh(float x) {
    x = fminf(fmaxf(x, -15.f), 15.f);
    float e = __expf(2.f * x);
    return __fdividef(e - 1.f, e + 1.f);
}
// sigmoid(CAP*tanh(g/CAP)) == sigmoid(g) to <0.002 for all g.
__device__ __forceinline__ float fast_sig(float g) {
    return __fdividef(1.f, 1.f + __expf(-g));
}

__device__ __forceinline__ void vmcnt0() {
    asm volatile("s_waitcnt vmcnt(0)" ::: "memory");
}
__device__ __forceinline__ void vmcnt8() {
    asm volatile("s_waitcnt vmcnt(8)" ::: "memory");
}

// ---------------- RMSNorm: x fp32 [ROWS][D] -> xn bf16 [ROWS][D] ----------------
__global__ __launch_bounds__(256) void rmsnorm_kernel(const float* __restrict__ x,
                                                      const float* __restrict__ w,
                                                      bf16_t* __restrict__ xn) {
    int row = blockIdx.x;
    int tid = threadIdx.x;
    const float4 v = ((const float4*)(x + (size_t)row * D_))[tid];
    float ss = v.x * v.x + v.y * v.y + v.z * v.z + v.w * v.w;
    #pragma unroll
    for (int off = 32; off > 0; off >>= 1) ss += __shfl_down(ss, off);
    __shared__ float red[4];
    if ((tid & 63) == 0) red[tid >> 6] = ss;
    __syncthreads();
    float tot = red[0] + red[1] + red[2] + red[3];
    float scale = rsqrtf(tot * (1.0f / (float)D_) + EPS_);
    const float4 wv = ((const float4*)w)[tid];
    bf16x4 o;
    o[0] = (bf16_t)(v.x * scale * wv.x);
    o[1] = (bf16_t)(v.y * scale * wv.y);
    o[2] = (bf16_t)(v.z * scale * wv.z);
    o[3] = (bf16_t)(v.w * scale * wv.w);
    ((bf16x4*)(xn + (size_t)row * D_))[tid] = o;
}

// ---- merged pack: W_gate+W_cell -> Wcat^T [NB_][D], and W_out -> Wout^T [D][KPAD_] ----
__global__ __launch_bounds__(256) void pack_all(const float* __restrict__ Wg,
                                                const float* __restrict__ Wc,
                                                const float* __restrict__ Wo,
                                                bf16_t* __restrict__ Wt,
                                                bf16_t* __restrict__ WtO) {
    __shared__ float tile[32][33];
    int tx = threadIdx.x & 31;
    int ty = threadIdx.x >> 5;
    int id = blockIdx.x;
    if (id < 32 * (NB_ / 32)) {          // pack_wcat part
        int kt = (id & 31) * 32;
        int nt = (id >> 5) * 32;
        #pragma unroll
        for (int i = 0; i < 4; i++) {
            int k = kt + ty + 8 * i;
            int n = nt + tx;
            float val = 0.f;
            if (n < P3_)      val = Wg[(size_t)k * P3_ + n];
            else if (n < NP_) val = Wc[(size_t)k * P_ + (n - P3_)];
            tile[ty + 8 * i][tx] = val;
        }
        __syncthreads();
        #pragma unroll
        for (int i = 0; i < 4; i++) {
            int n = nt + ty + 8 * i;
            int k = kt + tx;
            Wt[(size_t)n * D_ + k] = (bf16_t)tile[tx][ty + 8 * i];
        }
    } else {                              // pack_wout part
        int id2 = id - 32 * (NB_ / 32);
        int pt = (id2 % (KPAD_ / 32)) * 32;
        int dt = (id2 / (KPAD_ / 32)) * 32;
        #pragma unroll
        for (int i = 0; i < 4; i++) {
            int p = pt + ty + 8 * i;
            int d = dt + tx;
            float val = (p < P_) ? Wo[(size_t)p * D_ + d] : 0.f;
            tile[ty + 8 * i][tx] = val;
        }
        __syncthreads();
        #pragma unroll
        for (int i = 0; i < 4; i++) {
            int d = dt + ty + 8 * i;
            int p = pt + tx;
            WtO[(size_t)d * KPAD_ + p] = (bf16_t)tile[tx][ty + 8 * i];
        }
    }
}

// ---------------- 256x256 8-wave GEMM, 1 barrier/phase + spread staging (r12/r13) ----------------
// Per phase: {ds_reads; stage?; setprio; MFMA; setprio; barrier}. No pre-MFMA
// barrier (waves desync; m114 overlap). Quadrant order Q1(m0-3,n0-1)
// Q2(m0-3,n2-3) Q3(m4-7,n2-3) Q4(m4-7,n0-1); stage t+2 INTO BUF c as regions
// free: B-lo@ph2, A-lo@ph3, A-hi+B-hi@ph4. End-of-tile counted vmcnt(8)
// retires exactly t+1's 8 units (FIFO, T4); never drains mid-loop. No
// sched_barrier (m141), no per-phase lgkm drains (r9). Zero-conflict swizzle.
// Operand-swap mfma(B,A): lane acc quad = 4 consecutive output cols.
// NOTE r18 lesson: the uniform per-phase staging variant (A-hi@ph1 into the
// other buffer, vmcnt(6)) RACES despite a sound paper ledger — keep this
// clumped placement, verified correct across r13/r14/r17.
template <int KTOT, int LDA, int LDB, int LDC, int NX, int EPI>
__global__ __launch_bounds__(512, 2) void gemm8(const bf16_t* __restrict__ A,
                                                const bf16_t* __restrict__ Bt,
                                                const float* __restrict__ res,
                                                void* __restrict__ outv) {
    constexpr int NT = KTOT / 64;
    static_assert(NT >= 4, "NT >= 4");
    __shared__ __align__(16) char smem[131072];

    const int tid  = threadIdx.x;
    const int wid  = tid >> 6;
    const int lane = tid & 63;
    const int l15  = lane & 15;
    const int sl4  = lane >> 4;
    const int sp    = sl4 ^ ((lane >> 1) & 3);          // read 16B-slot swizzle
    const int chunk = (lane & 3) ^ ((lane >> 3) & 3);   // stage-source inverse swizzle
    const int wrow = (wid >> 2) * 128;
    const int wcol = (wid & 3) * 64;

    // XCD map (verified: FETCH ~= compulsory): xcd owns 8 by-rows, bx-outer
    constexpr int MCH = (ROWS_ / 256) / 8;   // 8
    const int bid = blockIdx.x;
    const int xcd = bid & 7;
    const int idx = bid >> 3;
    const int bx  = idx / MCH;
    const int by  = xcd * MCH + (idx - bx * MCH);
    const int m0 = by * 256, n0 = bx * 256;

    const int srow = wid * 16 + (lane >> 2);
    const bf16_t* Asrc = A  + (size_t)(m0 + srow) * LDA + chunk * 8;
    const bf16_t* Bsrc = Bt + (size_t)(n0 + srow) * LDB + chunk * 8;
    const unsigned ldsA0 = (unsigned)(wid * 1024);
    const unsigned ldsB0 = 32768u + (unsigned)(wid * 1024);

    // half-unit stages: 2 global_load_lds each (one per kk)
    auto stageAlo = [&](int kt, int buf) {   // A rows 0-127
        #pragma unroll
        for (int kk = 0; kk < 2; kk++)
            __builtin_amdgcn_global_load_lds(
                (const unsigned*)(Asrc + kt * 64 + kk * 32),
                (unsigned*)(smem + ((unsigned)buf * 65536u + (unsigned)kk * 16384u + ldsA0)), 16, 0, 0);
    };
    auto stageAhi = [&](int kt, int buf) {   // A rows 128-255
        #pragma unroll
        for (int kk = 0; kk < 2; kk++)
            __builtin_amdgcn_global_load_lds(
                (const unsigned*)(Asrc + (size_t)128 * LDA + kt * 64 + kk * 32),
                (unsigned*)(smem + ((unsigned)buf * 65536u + (unsigned)kk * 16384u + 8192u + ldsA0)), 16, 0, 0);
    };
    auto stageBlo = [&](int kt, int buf) {   // B rows (out-cols) 0-127
        #pragma unroll
        for (int kk = 0; kk < 2; kk++)
            __builtin_amdgcn_global_load_lds(
                (const unsigned*)(Bsrc + kt * 64 + kk * 32),
                (unsigned*)(smem + ((unsigned)buf * 65536u + (unsigned)kk * 16384u + ldsB0)), 16, 0, 0);
    };
    auto stageBhi = [&](int kt, int buf) {   // B rows 128-255
        #pragma unroll
        for (int kk = 0; kk < 2; kk++)
            __builtin_amdgcn_global_load_lds(
                (const unsigned*)(Bsrc + (size_t)128 * LDB + kt * 64 + kk * 32),
                (unsigned*)(smem + ((unsigned)buf * 65536u + (unsigned)kk * 16384u + 8192u + ldsB0)), 16, 0, 0);
    };
    auto ldA = [&](int buf, int kk, int m) -> bf16x8 {
        return *(const bf16x8*)(smem + (buf * 65536 + kk * 16384 +
                                        (wrow + m * 16 + l15) * 64 + sp * 16));
    };
    auto ldB = [&](int buf, int kk, int n) -> bf16x8 {
        return *(const bf16x8*)(smem + (buf * 65536 + 32768 + kk * 16384 +
                                        (wcol + n * 16 + l15) * 64 + sp * 16));
    };

    floatx4 acc[8][4];
    #pragma unroll
    for (int m = 0; m < 8; m++)
        #pragma unroll
        for (int n = 0; n < 4; n++) acc[m][n] = (floatx4){0.f, 0.f, 0.f, 0.f};

    bf16x8 aq[8];   // A: [0..3]=kk0 m-set, [4..7]=kk1 m-set (lo then hi, rotated ph3)
    bf16x8 bq[4];   // B n0-1: live ph1 -> ph4
    bf16x8 bq2[4];  // B n2-3

    // prologue: tiles 0,1 fully staged (16 loads); counted wait retires tile0
    stageAlo(0, 0); stageAhi(0, 0); stageBlo(0, 0); stageBhi(0, 0);
    stageAlo(1, 1); stageAhi(1, 1); stageBlo(1, 1); stageBhi(1, 1);
    vmcnt8();
    __builtin_amdgcn_s_barrier();

    for (int t = 0; t < NT; ++t) {
        const int c = t & 1;
        const bool st = (t + 2 < NT);

        // ---- ph1: 12 reads (A-lo both kk, B-lo both kk); MFMA Q1
        #pragma unroll
        for (int m = 0; m < 4; m++) { aq[m] = ldA(c, 0, m); aq[m + 4] = ldA(c, 1, m); }
        #pragma unroll
        for (int n = 0; n < 2; n++) { bq[n] = ldB(c, 0, n); bq[n + 2] = ldB(c, 1, n); }
        __builtin_amdgcn_s_setprio(1);
        #pragma unroll
        for (int m = 0; m < 4; m++)
            #pragma unroll
            for (int n = 0; n < 2; n++) {
                acc[m][n] = __builtin_amdgcn_mfma_f32_16x16x32_bf16(bq[n], aq[m], acc[m][n], 0, 0, 0);
                acc[m][n] = __builtin_amdgcn_mfma_f32_16x16x32_bf16(bq[n + 2], aq[m + 4], acc[m][n], 0, 0, 0);
            }
        __builtin_amdgcn_s_setprio(0);
        __builtin_amdgcn_s_barrier();   // all waves' A-lo/B-lo reads retired

        // ---- ph2: 4 reads (B-hi); stage B-lo(t+2) into freed region; MFMA Q2
        #pragma unroll
        for (int n = 0; n < 2; n++) { bq2[n] = ldB(c, 0, n + 2); bq2[n + 2] = ldB(c, 1, n + 2); }
        if (st) stageBlo(t + 2, c);
        __builtin_amdgcn_s_setprio(1);
        #pragma unroll
        for (int m = 0; m < 4; m++)
            #pragma unroll
            for (int n = 0; n < 2; n++) {
                acc[m][n + 2] = __builtin_amdgcn_mfma_f32_16x16x32_bf16(bq2[n], aq[m], acc[m][n + 2], 0, 0, 0);
                acc[m][n + 2] = __builtin_amdgcn_mfma_f32_16x16x32_bf16(bq2[n + 2], aq[m + 4], acc[m][n + 2], 0, 0, 0);
            }
        __builtin_amdgcn_s_setprio(0);
        __builtin_amdgcn_s_barrier();

        // ---- ph3: 8 reads (A-hi overwrite aq); stage A-lo(t+2); MFMA Q3
        #pragma unroll
        for (int m = 0; m < 4; m++) { aq[m] = ldA(c, 0, m + 4); aq[m + 4] = ldA(c, 1, m + 4); }
        if (st) stageAlo(t + 2, c);
        __builtin_amdgcn_s_setprio(1);
        #pragma unroll
        for (int m = 0; m < 4; m++)
            #pragma unroll
            for (int n = 0; n < 2; n++) {
                acc[m + 4][n + 2] = __builtin_amdgcn_mfma_f32_16x16x32_bf16(bq2[n], aq[m], acc[m + 4][n + 2], 0, 0, 0);
                acc[m + 4][n + 2] = __builtin_amdgcn_mfma_f32_16x16x32_bf16(bq2[n + 2], aq[m + 4], acc[m + 4][n + 2], 0, 0, 0);
            }
        __builtin_amdgcn_s_setprio(0);
        __builtin_amdgcn_s_barrier();   // all waves' A-hi/B-hi reads retired

        // ---- ph4: stage A-hi+B-hi(t+2); reg-only Q4; counted vmcnt; publish
        if (st) { stageAhi(t + 2, c); stageBhi(t + 2, c); }
        __builtin_amdgcn_s_setprio(1);
        #pragma unroll
        for (int m = 0; m < 4; m++)
            #pragma unroll
            for (int n = 0; n < 2; n++) {
                acc[m + 4][n] = __builtin_amdgcn_mfma_f32_16x16x32_bf16(bq[n], aq[m], acc[m + 4][n], 0, 0, 0);
                acc[m + 4][n] = __builtin_amdgcn_mfma_f32_16x16x32_bf16(bq[n + 2], aq[m + 4], acc[m + 4][n], 0, 0, 0);
            }
        __builtin_amdgcn_s_setprio(0);
        if (st)                vmcnt8();   // retire t+1's 8 units; t+2's stay in flight
        else if (t + 2 == NT)  vmcnt0();   // tail: only t+1's units outstanding
        __builtin_amdgcn_s_barrier();      // publish buf c^1
    }

    // transposed C/D (operand swap): lane holds rows m0+wrow+m*16+l15,
    // 4 consecutive cols n0+wcol+n*16+sl4*4 .. +3
    if constexpr (EPI == 0) {
        bf16_t* O = (bf16_t*)outv;
        #pragma unroll
        for (int m = 0; m < 8; m++) {
            const int row = m0 + wrow + m * 16 + l15;
            #pragma unroll
            for (int n = 0; n < 4; n++) {
                const int cb = n0 + wcol + n * 16 + sl4 * 4;
                if (cb < NP_) {           // packs never straddle NP_/P3_ (all %4==0)
                    const bool sg = cb < P3_;
                    bf16x4 o;
                    #pragma unroll
                    for (int r = 0; r < 4; r++) {
                        float g = acc[m][n][r];
                        o[r] = (bf16_t)(sg ? fast_sig(g) : fast_tanh(g));
                    }
                    *(bf16x4*)(O + (size_t)row * LDC + cb) = o;
                }
            }
        }
    } else {
        float* O = (float*)outv;
        #pragma unroll
        for (int m = 0; m < 8; m++) {
            const int row = m0 + wrow + m * 16 + l15;
            #pragma unroll
            for (int n = 0; n < 4; n++) {
                const int cb = n0 + wcol + n * 16 + sl4 * 4;
                const float4 rv = *(const float4*)(res + (size_t)row * LDC + cb);
                float4 ov;
                ov.x = rv.x + acc[m][n][0];
                ov.y = rv.y + acc[m][n][1];
                ov.z = rv.z + acc[m][n][2];
                ov.w = rv.w + acc[m][n][3];
                *(float4*)(O + (size_t)row * LDC + cb) = ov;
            }
        }
    }
}

// ---------------- chunked linear recurrence (r13/r14 form) ----------------
__global__ __launch_bounds__(256) void chunk_scan1(const bf16_t* __restrict__ act,
                                                   float* __restrict__ FA) {
    int p = blockIdx.x * 256 + threadIdx.x;
    int c = blockIdx.y;
    int b = blockIdx.z;
    if (p >= P_) return;
    const bf16_t* base = act + (size_t)(b * S_ + c * CLEN_) * NPAD_;
    float F = 1.f, Acc = 0.f;
    #pragma unroll 4
    for (int t = 0; t < CLEN_; t++) {
        const bf16_t* r = base + (size_t)t * NPAD_;
        float iv = (float)r[p];
        float fv = (float)r[P_ + p];
        float tc = (float)r[P3_ + p];
        Acc = fv * Acc + iv * tc;
        F *= fv;
    }
    size_t idx = (((size_t)b * CHUNKS_ + c) * P_ + p) * 2;
    FA[idx]     = F;
    FA[idx + 1] = Acc;
}

__global__ __launch_bounds__(256) void chunk_scan0(const float* __restrict__ FA,
                                                   const float* __restrict__ h0,
                                                   float* __restrict__ H0) {
    int p = blockIdx.x * 256 + threadIdx.x;
    int b = blockIdx.y;
    if (p >= P_) return;
    float h = h0[(size_t)b * P_ + p];
    for (int c = 0; c < CHUNKS_; c++) {
        H0[((size_t)b * CHUNKS_ + c) * P_ + p] = h;
        size_t idx = (((size_t)b * CHUNKS_ + c) * P_ + p) * 2;
        h = FA[idx + 1] + FA[idx] * h;
    }
}

__global__ __launch_bounds__(256) void chunk_scan2(const bf16_t* __restrict__ act,
                                                   const float* __restrict__ H0,
                                                   bf16_t* __restrict__ outp,
                                                   float* __restrict__ hs_out) {
    int p = blockIdx.x * 256 + threadIdx.x;
    int c = blockIdx.y;
    int b = blockIdx.z;
    if (p >= KPAD_) return;
    if (p >= P_) {
        bf16_t z = (bf16_t)0.f;
        for (int t = 0; t < CLEN_; t++)
            outp[(size_t)(b * S_ + c * CLEN_ + t) * KPAD_ + p] = z;
        return;
    }
    float h = H0[((size_t)b * CHUNKS_ + c) * P_ + p];
    if (c == 0) hs_out[(size_t)b * P_ + p] = h;   // fused copy_hidden (H0[0] == hs)
    const bf16_t* base = act + (size_t)(b * S_ + c * CLEN_) * NPAD_;
    bf16_t* ob = outp + (size_t)(b * S_ + c * CLEN_) * KPAD_;
    #pragma unroll 2
    for (int t = 0; t < CLEN_; t++) {
        const bf16_t* r = base + (size_t)t * NPAD_;
        float iv = (float)r[p];
        float fv = (float)r[P_ + p];
        float ov = (float)r[2 * P_ + p];
        float tc = (float)r[P3_ + p];
        h = fv * h + iv * tc;
        ob[(size_t)t * KPAD_ + p] = (bf16_t)(ov * fast_tanh(h));
    }
}

extern "C" void kernel_launch(void* const* d_in, const int* in_sizes, int n_in,
                              void* d_out, int out_size, void* d_ws, size_t ws_size,
                              hipStream_t stream) {
    const float* x   = (const float*)d_in[0];
    const float* hs  = (const float*)d_in[1];
    const float* lnw = (const float*)d_in[2];
    const float* Wg  = (const float*)d_in[3];
    const float* Wc  = (const float*)d_in[4];
    const float* Wo  = (const float*)d_in[5];
    float* out = (float*)d_out;

    char* ws = (char*)d_ws;
    size_t off = 0;
    auto alloc = [&](size_t bytes) {
        void* p = ws + off;
        off += (bytes + 255) & ~(size_t)255;
        return p;
    };
    bf16_t* xn_outp = (bf16_t*)alloc((size_t)ROWS_ * KPAD_ * 2);   // xn then outputs
    bf16_t* act     = (bf16_t*)alloc((size_t)ROWS_ * NPAD_ * 2);
    bf16_t* WcatT   = (bf16_t*)alloc((size_t)NB_ * D_ * 2);
    bf16_t* WoutT   = (bf16_t*)alloc((size_t)D_ * KPAD_ * 2);
    float*  FA      = (float*)alloc((size_t)B_ * CHUNKS_ * P_ * 2 * 4);
    float*  H0      = (float*)alloc((size_t)B_ * CHUNKS_ * P_ * 4);

    bf16_t* xn   = xn_outp;
    bf16_t* outp = xn_outp;

    hipLaunchKernelGGL(rmsnorm_kernel, dim3(ROWS_), dim3(256), 0, stream, x, lnw, xn);
    hipLaunchKernelGGL(pack_all, dim3(32 * (NB_ / 32) + (KPAD_ / 32) * (D_ / 32)),
                       dim3(256), 0, stream, Wg, Wc, Wo, WcatT, WoutT);

    hipLaunchKernelGGL((gemm8<D_, D_, D_, NPAD_, NB_ / 256, 0>),
                       dim3((NB_ / 256) * (ROWS_ / 256)), dim3(512), 0, stream,
                       xn, WcatT, (const float*)nullptr, (void*)act);

    hipLaunchKernelGGL(chunk_scan1, dim3(6, CHUNKS_, B_), dim3(256), 0, stream, act, FA);
    hipLaunchKernelGGL(chunk_scan0, dim3(6, B_), dim3(256), 0, stream, FA, hs, H0);
    hipLaunchKernelGGL(chunk_scan2, dim3(6, CHUNKS_, B_), dim3(256), 0, stream,
                       act, H0, outp, out + (size_t)ROWS_ * D_);

    hipLaunchKernelGGL((gemm8<KPAD_, KPAD_, KPAD_, D_, D_ / 256, 1>),
                       dim3((D_ / 256) * (ROWS_ / 256)), dim3(512), 0, stream,
                       outp, WoutT, x, d_out);
}